// Round 5
// baseline (203.072 us; speedup 1.0000x reference)
//
#include <hip/hip_runtime.h>

// SecureOptimizedBlockReLU (16,128,114,114) fp32 — two PERSISTENT grid-stride passes.
// sign = f32_block_sum > -1.0f (trunc/floordiv/shift chain preserves sign class;
// int16 wrap unreachable; row-major sequential sum order — absmax 0.0 R1-R4).
//
// R2-R4 all capped at ~2.4 TB/s with one-shot thread shapes (14k-26k short-lived
// blocks); fillBufferAligned hits 6.8 TB/s with persistent grid-stride waves.
// This version mirrors the fill shape: small grids, deep per-thread loops,
// multiple independent loads in flight, no LDS, no barriers.

typedef float v4 __attribute__((ext_vector_type(4)));
typedef float v2 __attribute__((ext_vector_type(2)));

#define PLANE 12996
#define P4 3249
#define M2STRIDE 64              // 2x2 mask: 57 rows x 57 cells, row stride 64
#define M2PLANE 3648             // 57*64
#define M4STRIDE 32              // 4x4 mask: 29 rows x 29 cells, row stride 32
#define M4PLANE 928              // 29*32
#define M4OFF 2801664            // 768 * M2PLANE
#define T2 1269504               // 768 planes * 57 rows * 29 units
#define T4 334080                // 768 planes * 29 rows * 15 units
#define TT (T2 + T4)

// ---- pass 1: block-sign masks (persistent, no LDS) ----
__global__ __launch_bounds__(256) void mask_kernel(const float* __restrict__ in,
                                                   unsigned char* __restrict__ ws) {
    const int G = 1024 * 256;
    for (int u = blockIdx.x * 256 + threadIdx.x; u < TT; u += G) {
        if (u < T2) {
            // 2x2: unit = (plane, block-row r, col-pair j); j<28 -> cells 2j,2j+1
            int p = u / 1653;            // 57*29
            int rest = u - p * 1653;
            int r = rest / 29;
            int j = rest - r * 29;
            int n = p / 48, cr = p - n * 48;
            const float* bp = in + (size_t)(n * 128 + 32 + cr) * PLANE + 228 * r;
            unsigned char* mp = ws + (size_t)p * M2PLANE + M2STRIDE * r;
            if (j < 28) {
                int w0 = 4 * j;
                v4 a  = *(const v4*)(bp + w0);            // row 2r (16B aligned)
                v2 b0 = *(const v2*)(bp + w0 + 114);      // row 2r+1 (8B aligned)
                v2 b1 = *(const v2*)(bp + w0 + 116);
                float s0 = ((a.x + a.y) + b0.x) + b0.y;   // row-major sequential
                float s1 = ((a.z + a.w) + b1.x) + b1.y;
                unsigned short m = (unsigned short)((s0 > -1.0f) ? 1 : 0)
                                 | (unsigned short)(((s1 > -1.0f) ? 1 : 0) << 8);
                *(unsigned short*)(mp + 2 * j) = m;
            } else {
                v2 a = *(const v2*)(bp + 112);
                v2 b = *(const v2*)(bp + 226);
                float s = ((a.x + a.y) + b.x) + b.y;
                mp[56] = (s > -1.0f) ? 1 : 0;
            }
        } else {
            // 4x4: unit = (plane, block-row r, col-pair jp); jp<14 -> cells 2jp,2jp+1
            int v = u - T2;
            int p = v / 435;             // 29*15
            int rest = v - p * 435;
            int r = rest / 15;
            int jp = rest - r * 15;
            int n = p / 48, cr = p - n * 48;
            const float* bp = in + (size_t)(n * 128 + 80 + cr) * PLANE;
            unsigned char* mp = ws + M4OFF + (size_t)p * M4PLANE + M4STRIDE * r;
            int h0 = 4 * r;
            int nh = (r == 28) ? 2 : 4;
            if (jp < 14) {
                int w0 = 8 * jp;
                float s0 = 0.0f, s1 = 0.0f;
                for (int k = 0; k < nh; ++k) {
                    const float* rp = bp + (h0 + k) * 114 + w0;
                    if ((k & 1) == 0) {                   // offset ≡0 mod 4
                        v4 x = *(const v4*)rp;
                        v4 y = *(const v4*)(rp + 4);
                        s0 = (((s0 + x.x) + x.y) + x.z) + x.w;
                        s1 = (((s1 + y.x) + y.y) + y.z) + y.w;
                    } else {                              // offset ≡2 mod 4
                        v2 x0 = *(const v2*)rp;
                        v2 x1 = *(const v2*)(rp + 2);
                        v2 y0 = *(const v2*)(rp + 4);
                        v2 y1 = *(const v2*)(rp + 6);
                        s0 = (((s0 + x0.x) + x0.y) + x1.x) + x1.y;
                        s1 = (((s1 + y0.x) + y0.y) + y1.x) + y1.y;
                    }
                }
                unsigned short m = (unsigned short)((s0 > -1.0f) ? 1 : 0)
                                 | (unsigned short)(((s1 > -1.0f) ? 1 : 0) << 8);
                *(unsigned short*)(mp + 2 * jp) = m;
            } else {
                float s = 0.0f;
                for (int k = 0; k < nh; ++k) {
                    v2 x = *(const v2*)(bp + (h0 + k) * 114 + 112);
                    s = (s + x.x) + x.y;
                }
                mp[28] = (s > -1.0f) ? 1 : 0;
            }
        }
    }
}

// ---- pass 2: persistent unrolled copy + mask apply ----
#define G2 524288                // 2048 blocks * 256
#define N4 6653952               // total float4 = G2*12 + 362496

__device__ __forceinline__ v4 apply_one(int i, v4 v, const unsigned char* __restrict__ ws) {
    int plane = i / P4;
    int rr = i - plane * P4;
    int c = plane & 127;
    if (c < 32) return v;
    int q = 4 * rr;
    int h = q / 114;
    int w0 = q - h * 114;        // even
    int i0, i1;
    const unsigned char* mb;
    if (c < 80) {
        mb = ws + (size_t)((plane >> 7) * 48 + (c - 32)) * M2PLANE;
        i0 = M2STRIDE * (h >> 1) + (w0 >> 1);
        i1 = (w0 <= 110) ? (M2STRIDE * (h >> 1) + ((w0 + 2) >> 1))
                         : (M2STRIDE * ((h + 1) >> 1));   // straddle -> next row, cell 0
    } else {
        mb = ws + M4OFF + (size_t)((plane >> 7) * 48 + (c - 80)) * M4PLANE;
        i0 = M4STRIDE * (h >> 2) + (w0 >> 2);
        i1 = (w0 <= 110) ? (M4STRIDE * (h >> 2) + ((w0 + 2) >> 2))
                         : (M4STRIDE * ((h + 1) >> 2));
    }
    float m0 = (float)mb[i0];    // elements 0,1 share a cell (w0 even)
    float m1 = (float)mb[i1];    // elements 2,3 share a cell
    v4 o;
    o.x = v.x * m0; o.y = v.y * m0; o.z = v.z * m1; o.w = v.w * m1;
    return o;
}

__global__ __launch_bounds__(256) void apply_kernel(const float* __restrict__ in,
                                                    const unsigned char* __restrict__ ws,
                                                    float* __restrict__ out) {
    const v4* __restrict__ ip = (const v4*)in;
    v4* __restrict__ op = (v4*)out;
    const int base = blockIdx.x * 256 + threadIdx.x;
#pragma unroll
    for (int g = 0; g < 3; ++g) {
        int i0 = base + (4 * g) * G2;
        v4 a = ip[i0];
        v4 b = ip[i0 + G2];
        v4 cc = ip[i0 + 2 * G2];
        v4 d = ip[i0 + 3 * G2];
        op[i0]          = apply_one(i0,          a,  ws);
        op[i0 + G2]     = apply_one(i0 + G2,     b,  ws);
        op[i0 + 2 * G2] = apply_one(i0 + 2 * G2, cc, ws);
        op[i0 + 3 * G2] = apply_one(i0 + 3 * G2, d,  ws);
    }
    int it = base + 12 * G2;
    if (it < N4) {
        v4 v = ip[it];
        op[it] = apply_one(it, v, ws);
    }
}

extern "C" void kernel_launch(void* const* d_in, const int* in_sizes, int n_in,
                              void* d_out, int out_size, void* d_ws, size_t ws_size,
                              hipStream_t stream) {
    const float* in = (const float*)d_in[0];
    float* out = (float*)d_out;
    unsigned char* ws = (unsigned char*)d_ws;
    mask_kernel<<<1024, 256, 0, stream>>>(in, ws);
    apply_kernel<<<2048, 256, 0, stream>>>(in, ws, out);
}

// Round 6
// 202.950 us; speedup vs baseline: 1.0006x; 1.0006x over previous
//
#include <hip/hip_runtime.h>

// SecureOptimizedBlockReLU (16,128,114,114) fp32 — single fused pass, copy-shaped.
// ch 0-31 passthrough; ch 32-79 2x2 block sign; ch 80-127 4x4 (zero-padded edges).
// sign = f32_block_sum > -1.0f (trunc/floordiv/shift chain preserves sign class;
// int16 wrap unreachable; row-major sequential sum order — absmax 0.0 R1-R5).
//
// R2 redux with the one defect removed: odd rows (8B-aligned) are single
// dwordx4 accesses via align(4) vector types, not float2 pairs. Every global
// access is 16B/lane, wave-dense. No LDS, no barriers, no ws.

typedef float v4  __attribute__((ext_vector_type(4)));
typedef float v2  __attribute__((ext_vector_type(2)));
typedef float uv4 __attribute__((ext_vector_type(4), aligned(4)));  // dwordx4 @ 8B-aligned addrs

#define PLANE 12996
#define NBLK_A 6498   // 16*32*3249 float4 / 256 (exact)
#define NBLK_B 4959   // 768 planes * 57 strips * 29 units / 256 (exact)
#define NBLK_C 2523   // 768 planes * 841 units / 256 (exact)

__global__ __launch_bounds__(256) void sbrelu_fused2(const float* __restrict__ in,
                                                     float* __restrict__ out) {
    const int bid = blockIdx.x;
    const int tid = threadIdx.x;

    if (bid < NBLK_A) {
        // ---- class A: ch 0..31 pure float4 copy ----
        int idx = bid * 256 + tid;
        int n = idx / 103968;                  // 32*3249 float4 per n
        int off = n * 415872 + (idx - n * 103968);
        v4 v = ((const v4*)in)[off];
        __builtin_nontemporal_store(v, &((v4*)out)[off]);
        return;
    }
    if (bid < NBLK_A + NBLK_B) {
        // ---- class B: 2x2. unit = 4w x 2h (two blocks); 57 strips x 29 units ----
        int u = (bid - NBLK_A) * 256 + tid;
        int plane = u / 1653;                  // 57*29
        int rest  = u - plane * 1653;
        int r = rest / 29;
        int j = rest - r * 29;
        int n = plane / 48;
        int c = plane - n * 48 + 32;
        const float* bi = in  + (size_t)(n * 128 + c) * PLANE + 228 * r;
        float*       bo = out + (size_t)(n * 128 + c) * PLANE + 228 * r;
        if (j < 28) {
            int w = 4 * j;
            v4 a = *(const v4*)(bi + w);            // row 2r   (16B aligned)
            v4 b = *(const uv4*)(bi + w + 114);     // row 2r+1 (8B aligned, dwordx4)
            float s0 = ((a.x + a.y) + b.x) + b.y;   // row-major sequential
            float s1 = ((a.z + a.w) + b.z) + b.w;
            float m0 = (s0 > -1.0f) ? 1.0f : 0.0f;
            float m1 = (s1 > -1.0f) ? 1.0f : 0.0f;
            v4 oa = {a.x*m0, a.y*m0, a.z*m1, a.w*m1};
            v4 ob = {b.x*m0, b.y*m0, b.z*m1, b.w*m1};
            __builtin_nontemporal_store(oa, (v4*)(bo + w));
            __builtin_nontemporal_store(ob, (uv4*)(bo + w + 114));
        } else {
            // last 2 cols (112,113)
            v2 a = *(const v2*)(bi + 112);
            v2 b = *(const v2*)(bi + 226);
            float s = ((a.x + a.y) + b.x) + b.y;
            float m = (s > -1.0f) ? 1.0f : 0.0f;
            v2 oa = {a.x*m, a.y*m};
            v2 ob = {b.x*m, b.y*m};
            __builtin_nontemporal_store(oa, (v2*)(bo + 112));
            __builtin_nontemporal_store(ob, (v2*)(bo + 226));
        }
        return;
    }
    {
        // ---- class C: 4x4. unit = one block; 29x29 units (edges 2-wide/2-tall) ----
        int u = (bid - NBLK_A - NBLK_B) * 256 + tid;
        int plane = u / 841;                   // 29*29
        int rest  = u - plane * 841;
        int bh = rest / 29;
        int bw = rest - bh * 29;
        int n = plane / 48;
        int c = plane - n * 48 + 80;
        const float* bp = in  + (size_t)(n * 128 + c) * PLANE + 456 * bh;
        float*       op = out + (size_t)(n * 128 + c) * PLANE + 456 * bh;
        const int nh = (bh == 28) ? 2 : 4;
        if (bw < 28) {
            int w = 4 * bw;
            v4 x0, x1, x2, x3;
            x0 = *(const v4*)(bp + w);          // even rows 16B-aligned
            x1 = *(const uv4*)(bp + w + 114);   // odd rows 8B-aligned dwordx4
            float s = ((x0.x + x0.y) + x0.z) + x0.w;          // row-major sequential
            s = (((s + x1.x) + x1.y) + x1.z) + x1.w;
            if (nh == 4) {
                x2 = *(const v4*)(bp + w + 228);
                x3 = *(const uv4*)(bp + w + 342);
                s = (((s + x2.x) + x2.y) + x2.z) + x2.w;
                s = (((s + x3.x) + x3.y) + x3.z) + x3.w;
            }
            float m = (s > -1.0f) ? 1.0f : 0.0f;
            v4 o0 = {x0.x*m, x0.y*m, x0.z*m, x0.w*m};
            v4 o1 = {x1.x*m, x1.y*m, x1.z*m, x1.w*m};
            __builtin_nontemporal_store(o0, (v4*)(op + w));
            __builtin_nontemporal_store(o1, (uv4*)(op + w + 114));
            if (nh == 4) {
                v4 o2 = {x2.x*m, x2.y*m, x2.z*m, x2.w*m};
                v4 o3 = {x3.x*m, x3.y*m, x3.z*m, x3.w*m};
                __builtin_nontemporal_store(o2, (v4*)(op + w + 228));
                __builtin_nontemporal_store(o3, (uv4*)(op + w + 342));
            }
        } else {
            // last 2 cols (112,113); all offsets 8B-aligned
            v2 y0, y1, y2, y3;
            y0 = *(const v2*)(bp + 112);
            y1 = *(const v2*)(bp + 226);
            float s = ((y0.x + y0.y) + y1.x) + y1.y;
            if (nh == 4) {
                y2 = *(const v2*)(bp + 340);
                y3 = *(const v2*)(bp + 454);
                s = (((s + y2.x) + y2.y) + y3.x) + y3.y;
            }
            float m = (s > -1.0f) ? 1.0f : 0.0f;
            v2 o0 = {y0.x*m, y0.y*m};
            v2 o1 = {y1.x*m, y1.y*m};
            __builtin_nontemporal_store(o0, (v2*)(op + 112));
            __builtin_nontemporal_store(o1, (v2*)(op + 226));
            if (nh == 4) {
                v2 o2 = {y2.x*m, y2.y*m};
                v2 o3 = {y3.x*m, y3.y*m};
                __builtin_nontemporal_store(o2, (v2*)(op + 340));
                __builtin_nontemporal_store(o3, (v2*)(op + 454));
            }
        }
    }
}

extern "C" void kernel_launch(void* const* d_in, const int* in_sizes, int n_in,
                              void* d_out, int out_size, void* d_ws, size_t ws_size,
                              hipStream_t stream) {
    const float* in = (const float*)d_in[0];
    float* out = (float*)d_out;
    sbrelu_fused2<<<NBLK_A + NBLK_B + NBLK_C, 256, 0, stream>>>(in, out);
}

// Round 7
// 187.339 us; speedup vs baseline: 1.0840x; 1.0833x over previous
//
#include <hip/hip_runtime.h>

// SecureOptimizedBlockReLU (16,128,114,114) fp32 — strip-linear fused kernel.
// ch 0-31 passthrough; ch 32-79 2x2 block sign; ch 80-127 4x4 (zero-padded edges).
// sign = f32_block_sum > -1.0f (trunc/floordiv/shift chain preserves sign class;
// int16 wrap unreachable; row-major sequential sum order — absmax 0.0 R1-R6).
//
// Evidence trail: fused multi-stream kernels = 3.1 TB/s logical; R4's linear
// copy-shaped apply = ~4.3; R3's linear plane kernel died of 2 wg/CU phase
// serialization. This kernel: one wg per 12-row strip (6.8 KB LDS -> 8 wg/CU),
// contiguous float4 load stream -> LDS -> masks -> contiguous store stream.

typedef float v4 __attribute__((ext_vector_type(4)));

#define PLANE 12996
#define NBLK_A 6498    // 16*32*3249 float4 / 256 (exact)
#define NBLK_B 7680    // 768 planes * 10 strips
#define NBLK_C 7680

__global__ __launch_bounds__(256) void sbrelu_strip(const float* __restrict__ in,
                                                    float* __restrict__ out) {
    __shared__ v4 Ls[342];      // 12 rows * 114 floats = 342 float4 (5472 B)
    __shared__ float Lm[342];   // per-cell masks (1368 B)
    const int bid = blockIdx.x;
    const int tid = threadIdx.x;

    if (bid < NBLK_A) {
        // ---- class A: ch 0..31 pure float4 copy (wg-uniform path, no barriers) ----
        int idx = bid * 256 + tid;
        int n = idx / 103968;                 // 32*3249 float4 per n
        int off = n * 415872 + (idx - n * 103968);
        ((v4*)out)[off] = ((const v4*)in)[off];
        return;
    }

    int u, cls;
    if (bid < NBLK_A + NBLK_B) { u = bid - NBLK_A; cls = 0; }
    else                       { u = bid - NBLK_A - NBLK_B; cls = 1; }
    const int p  = u / 10;                    // plane 0..767
    const int r  = u - 10 * p;                // strip 0..9 (consecutive bids = consecutive strips)
    const int n  = p / 48;
    const int cr = p - n * 48;
    const int c  = cls ? (80 + cr) : (32 + cr);
    const int nrows = (r < 9) ? 12 : 6;       // tail strip rows 108..113
    const int nf4 = (nrows * 114) >> 2;       // 342 or 171 (12*114 and 6*114 both mult of 4)

    const v4* __restrict__ ip = (const v4*)(in  + (size_t)(n * 128 + c) * PLANE + 12 * r * 114);
    v4* __restrict__       op = (v4*)(out + (size_t)(n * 128 + c) * PLANE + 12 * r * 114);

    // ---- phase 1: contiguous linear load stream -> LDS ----
    for (int i = tid; i < nf4; i += 256) Ls[i] = ip[i];
    __syncthreads();

    // ---- phase 2: masks (bit-exact row-major sequential sums, as R1-R6) ----
    const float* Lf = (const float*)Ls;
    if (cls == 0) {
        int ncell = (nrows >> 1) * 57;        // 342 or 171
        for (int m = tid; m < ncell; m += 256) {
            int br = m / 57;
            int cw = m - 57 * br;
            const float* q0 = Lf + 228 * br + 2 * cw;
            float s = ((q0[0] + q0[1]) + q0[114]) + q0[115];
            Lm[m] = (s > -1.0f) ? 1.0f : 0.0f;
        }
    } else {
        int ncell = ((r < 9) ? 3 : 2) * 29;   // 87 or 58
        for (int m = tid; m < ncell; m += 256) {
            int br = m / 29;
            int cw = m - 29 * br;
            int nh = (3 * r + br == 28) ? 2 : 4;   // global block-row 28 is 2-tall
            int nw = (cw == 28) ? 2 : 4;
            const float* q0 = Lf + 456 * br + 4 * cw;
            float s = 0.0f;
            for (int k = 0; k < nh; ++k)
                for (int j = 0; j < nw; ++j) s += q0[114 * k + j];
            Lm[m] = (s > -1.0f) ? 1.0f : 0.0f;
        }
    }
    __syncthreads();

    // ---- phase 3: contiguous linear masked store stream ----
    if (cls == 0) {
        for (int i = tid; i < nf4; i += 256) {
            v4 v = Ls[i];
            int q = 4 * i;
            int hl = q / 114;
            int w  = q - 114 * hl;
            v4 o;
#pragma unroll
            for (int e = 0; e < 4; ++e) {
                o[e] = v[e] * Lm[(hl >> 1) * 57 + (w >> 1)];
                if (++w == 114) { w = 0; ++hl; }   // float4 may straddle rows
            }
            op[i] = o;
        }
    } else {
        for (int i = tid; i < nf4; i += 256) {
            v4 v = Ls[i];
            int q = 4 * i;
            int hl = q / 114;
            int w  = q - 114 * hl;
            v4 o;
#pragma unroll
            for (int e = 0; e < 4; ++e) {
                o[e] = v[e] * Lm[(hl >> 2) * 29 + (w >> 2)];
                if (++w == 114) { w = 0; ++hl; }
            }
            op[i] = o;
        }
    }
}

extern "C" void kernel_launch(void* const* d_in, const int* in_sizes, int n_in,
                              void* d_out, int out_size, void* d_ws, size_t ws_size,
                              hipStream_t stream) {
    const float* in = (const float*)d_in[0];
    float* out = (float*)d_out;
    sbrelu_strip<<<NBLK_A + NBLK_B + NBLK_C, 256, 0, stream>>>(in, out);
}